// Round 5
// baseline (397.699 us; speedup 1.0000x reference)
//
#include <hip/hip_runtime.h>

#define NN 10000
#define BB 8
#define EE 160000
#define DH 128
#define LN_EPS 1e-5f

typedef unsigned short ushort_t;
typedef unsigned int uint_t;

typedef __bf16 bf16x8 __attribute__((ext_vector_type(8)));
typedef float floatx4 __attribute__((ext_vector_type(4)));

__device__ __forceinline__ float b2f(uint_t u) { return __uint_as_float(u << 16); }
__device__ __forceinline__ ushort_t f2b(float f) {
    uint_t u = __float_as_uint(f);
    return (ushort_t)((u + 0x7fffu + ((u >> 16) & 1u)) >> 16);
}
__device__ __forceinline__ uint_t pack2(float lo, float hi) {
    return (uint_t)f2b(lo) | ((uint_t)f2b(hi) << 16);
}
__device__ __forceinline__ float sigm(float x) { return 1.0f / (1.0f + __expf(-x)); }
__device__ __forceinline__ float tanh_fast(float x) {
    float ex = __expf(2.0f * x);
    return 1.0f - 2.0f / (ex + 1.0f);
}

// ---------------- CSR build ----------------

__global__ void count_deg(const int* __restrict__ ei, int* __restrict__ cnt) {
    int e = blockIdx.x * 256 + threadIdx.x;
    if (e < EE) atomicAdd(&cnt[ei[EE + e]], 1);
}

__global__ __launch_bounds__(256) void scan1(const int* __restrict__ cnt,
                                             int* __restrict__ offs,
                                             int* __restrict__ bsum) {
    __shared__ int s[256];
    const int t = threadIdx.x, idx = blockIdx.x * 256 + t;
    int x = (idx < NN) ? cnt[idx] : 0;
    s[t] = x;
    __syncthreads();
    for (int o = 1; o < 256; o <<= 1) {
        int v = s[t];
        int u = (t >= o) ? s[t - o] : 0;
        __syncthreads();
        s[t] = v + u;
        __syncthreads();
    }
    if (idx < NN) offs[idx] = s[t] - x;  // block-local exclusive
    if (t == 255) bsum[blockIdx.x] = s[255];
}

__global__ __launch_bounds__(64) void scan2(int* __restrict__ bsum, int* __restrict__ offs) {
    __shared__ int sb[40];
    const int t = threadIdx.x;
    if (t < 40) sb[t] = bsum[t];
    __syncthreads();
    if (t == 0) {
        int acc = 0;
        for (int i = 0; i < 40; ++i) {
            int v = sb[i];
            sb[i] = acc;
            acc += v;
        }
        offs[NN] = EE;
    }
    __syncthreads();
    if (t < 40) bsum[t] = sb[t];
}

__global__ __launch_bounds__(256) void scan3(const int* __restrict__ cnt,
                                             const int* __restrict__ bsum,
                                             int* __restrict__ offs,
                                             int* __restrict__ cursor,
                                             float* __restrict__ dis) {
    const int idx = blockIdx.x * 256 + threadIdx.x;
    if (idx < NN) {
        int off = offs[idx] + bsum[blockIdx.x];
        offs[idx] = off;
        cursor[idx] = off;
        dis[idx] = rsqrtf((float)(cnt[idx] + 1));
    }
}

// csr: src index + bf16(dis[src]) weight
__global__ void fill_csr(const int* __restrict__ ei, int* __restrict__ cursor,
                         const float* __restrict__ dis, int* __restrict__ csr_src,
                         ushort_t* __restrict__ csr_w) {
    int e = blockIdx.x * 256 + threadIdx.x;
    if (e < EE) {
        int s = ei[e];
        int d = ei[EE + e];
        int pos = atomicAdd(&cursor[d], 1);
        csr_src[pos] = s;
        csr_w[pos] = f2b(dis[s]);
    }
}

// ---------------- weight transpose+convert: Wt[col][k] bf16 ----------------

__global__ __launch_bounds__(256) void wt_k(const float* __restrict__ Wz,
                                            const float* __restrict__ Wr,
                                            const float* __restrict__ Wc,
                                            ushort_t* __restrict__ Wt_zr,
                                            ushort_t* __restrict__ Wt_c) {
    const int col = blockIdx.x, k = threadIdx.x;
    if (col < 256) {
        float v = (col < 128) ? Wz[(size_t)k * 128 + col] : Wr[(size_t)k * 128 + col - 128];
        Wt_zr[(size_t)col * 256 + k] = f2b(v);
    } else {
        int c2 = col - 256;
        Wt_c[(size_t)c2 * 256 + k] = f2b(Wc[(size_t)k * 128 + c2]);
    }
}

// ---------------- gather_xh: 256-wide f32 gather of [x|h] -> agg_x, agg_h (bf16) ----
// agg = dis[n] * ( sum_e dis[s]*row[s] + dis[n]*row[n] ). One wave per (b,n).
// Lanes 0-31 handle x (cols 0-127), lanes 32-63 handle h.

__global__ __launch_bounds__(256) void gather_xh(
    const float* __restrict__ x, const float* __restrict__ h,
    const int* __restrict__ offs, const int* __restrict__ csr_src,
    const ushort_t* __restrict__ csr_w, const float* __restrict__ dis,
    ushort_t* __restrict__ agg_x, ushort_t* __restrict__ agg_h) {
    const int tid = threadIdx.x, lane = tid & 63;
    const int b = blockIdx.x & 7;
    const int n = (blockIdx.x >> 3) * 4 + (tid >> 6);
    const int il = lane & 31;
    const char* base = (const char*)((lane < 32) ? x : h) +
                       (size_t)b * NN * 512 + (size_t)il * 16;

    const float dn = dis[n];
    float a0, a1, a2, a3;
    {
        float4 v = *(const float4*)(base + (size_t)n * 512);
        a0 = dn * v.x; a1 = dn * v.y; a2 = dn * v.z; a3 = dn * v.w;
    }

    int e = offs[n];
    const int e1 = offs[n + 1];
    for (; e + 8 <= e1; e += 8) {
        int ss[8]; float ww[8]; float4 vv[8];
#pragma unroll
        for (int i = 0; i < 8; ++i) ss[i] = csr_src[e + i];
#pragma unroll
        for (int i = 0; i < 8; ++i) ww[i] = b2f((uint_t)csr_w[e + i]);
#pragma unroll
        for (int i = 0; i < 8; ++i) vv[i] = *(const float4*)(base + (size_t)ss[i] * 512);
#pragma unroll
        for (int i = 0; i < 8; ++i) {
            a0 += ww[i] * vv[i].x; a1 += ww[i] * vv[i].y;
            a2 += ww[i] * vv[i].z; a3 += ww[i] * vv[i].w;
        }
    }
    for (; e < e1; ++e) {
        int s_ = csr_src[e];
        float w_ = b2f((uint_t)csr_w[e]);
        float4 v = *(const float4*)(base + (size_t)s_ * 512);
        a0 += w_ * v.x; a1 += w_ * v.y; a2 += w_ * v.z; a3 += w_ * v.w;
    }
    a0 *= dn; a1 *= dn; a2 *= dn; a3 *= dn;

    ushort_t* dst = ((lane < 32) ? agg_x : agg_h) + ((size_t)b * NN + n) * 128 + il * 4;
    uint2 st;
    st.x = pack2(a0, a1);
    st.y = pack2(a2, a3);
    *(uint2*)dst = st;
}

// ---------------- gather_rh: 128-wide bf16 gather of r*h -> agg_rh (bf16) ----------

__global__ __launch_bounds__(256) void gather_rh(
    const ushort_t* __restrict__ rh, const int* __restrict__ offs,
    const int* __restrict__ csr_src, const ushort_t* __restrict__ csr_w,
    const float* __restrict__ dis, ushort_t* __restrict__ agg_rh) {
    const int tid = threadIdx.x, lane = tid & 63;
    const int b = blockIdx.x & 7;
    const int n = (blockIdx.x >> 3) * 4 + (tid >> 6);
    const ushort_t* base = rh + (size_t)b * NN * 128 + lane * 2;

    const float dn = dis[n];
    float a0, a1;
    {
        uint_t u = *(const uint_t*)(base + (size_t)n * 128);
        a0 = dn * b2f(u & 0xffffu);
        a1 = dn * __uint_as_float(u & 0xffff0000u);
    }

    int e = offs[n];
    const int e1 = offs[n + 1];
    for (; e + 8 <= e1; e += 8) {
        int ss[8]; float ww[8]; uint_t uu[8];
#pragma unroll
        for (int i = 0; i < 8; ++i) ss[i] = csr_src[e + i];
#pragma unroll
        for (int i = 0; i < 8; ++i) ww[i] = b2f((uint_t)csr_w[e + i]);
#pragma unroll
        for (int i = 0; i < 8; ++i) uu[i] = *(const uint_t*)(base + (size_t)ss[i] * 128);
#pragma unroll
        for (int i = 0; i < 8; ++i) {
            a0 += ww[i] * b2f(uu[i] & 0xffffu);
            a1 += ww[i] * __uint_as_float(uu[i] & 0xffff0000u);
        }
    }
    for (; e < e1; ++e) {
        int s_ = csr_src[e];
        float w_ = b2f((uint_t)csr_w[e]);
        uint_t u = *(const uint_t*)(base + (size_t)s_ * 128);
        a0 += w_ * b2f(u & 0xffffu);
        a1 += w_ * __uint_as_float(u & 0xffff0000u);
    }
    a0 *= dn; a1 *= dn;

    *(uint_t*)(agg_rh + ((size_t)b * NN + n) * 128 + lane * 2) = pack2(a0, a1);
}

// ---------------- GEMM 128x128 tile, K=256 = [A1 | A2] @ Wt, fused epilogues ------
// PHASE 0: mode=blockIdx.y (0: z=sigma->z_buf bf16; 1: r=sigma, rh=r*h->rh bf16)
// PHASE 1: mode 2: tanh, GRU blend, LayerNorm -> out f32

template <int PHASE>
__global__ __launch_bounds__(256) void gemm_k(
    const ushort_t* __restrict__ A1, const ushort_t* __restrict__ A2,
    const ushort_t* __restrict__ Wt, const float* __restrict__ bz,
    const float* __restrict__ br, const float* __restrict__ bc,
    const float* __restrict__ h_prev, const ushort_t* __restrict__ z_in,
    const float* __restrict__ gamma, const float* __restrict__ beta,
    ushort_t* __restrict__ z_out, ushort_t* __restrict__ rh_out,
    float* __restrict__ f_out) {
    __shared__ __align__(16) ushort_t As[128 * 72];
    __shared__ __align__(16) ushort_t Bs[128 * 72];
    const int tid = threadIdx.x;
    const int rb0 = blockIdx.x * 128;
    const int mode = (PHASE == 1) ? 2 : blockIdx.y;
    const int cb0 = (mode == 1) ? 128 : 0;

    const int wv = tid >> 6, lane = tid & 63;
    const int l15 = lane & 15, q = lane >> 4;
    const int sr = tid >> 1;
    const int kh = (tid & 1) * 32;

    floatx4 acc[2][8];
#pragma unroll
    for (int i = 0; i < 2; ++i)
#pragma unroll
        for (int j = 0; j < 8; ++j) acc[i][j] = (floatx4){0.f, 0.f, 0.f, 0.f};

    for (int k0 = 0; k0 < 256; k0 += 64) {
        {
            const int kg = k0 + kh;
            const ushort_t* s = (kg < 128) ? (A1 + (size_t)(rb0 + sr) * 128 + kg)
                                           : (A2 + (size_t)(rb0 + sr) * 128 + (kg - 128));
            ushort_t* dst = &As[sr * 72 + kh];
#pragma unroll
            for (int i = 0; i < 4; ++i) *(uint4*)(dst + i * 8) = *(const uint4*)(s + i * 8);
        }
        {
            const ushort_t* s = Wt + (size_t)(cb0 + sr) * 256 + k0 + kh;
            ushort_t* dst = &Bs[sr * 72 + kh];
#pragma unroll
            for (int i = 0; i < 4; ++i) *(uint4*)(dst + i * 8) = *(const uint4*)(s + i * 8);
        }
        __syncthreads();
#pragma unroll
        for (int ks = 0; ks < 2; ++ks) {
            const int ko = ks * 32 + q * 8;
            bf16x8 a0 = *(const bf16x8*)&As[(wv * 32 + l15) * 72 + ko];
            bf16x8 a1 = *(const bf16x8*)&As[(wv * 32 + 16 + l15) * 72 + ko];
#pragma unroll
            for (int j = 0; j < 8; ++j) {
                bf16x8 b = *(const bf16x8*)&Bs[(j * 16 + l15) * 72 + ko];
                acc[0][j] = __builtin_amdgcn_mfma_f32_16x16x32_bf16(a0, b, acc[0][j], 0, 0, 0);
                acc[1][j] = __builtin_amdgcn_mfma_f32_16x16x32_bf16(a1, b, acc[1][j], 0, 0, 0);
            }
        }
        __syncthreads();
    }

    // C/D: col = j*16 + l15, row = rb0 + wv*32 + i*16 + q*4 + v
    if (mode == 0) {
        float bv[8];
#pragma unroll
        for (int j = 0; j < 8; ++j) bv[j] = bz[j * 16 + l15];
#pragma unroll
        for (int i = 0; i < 2; ++i)
#pragma unroll
            for (int j = 0; j < 8; ++j)
#pragma unroll
                for (int v = 0; v < 4; ++v) {
                    int row = rb0 + wv * 32 + i * 16 + q * 4 + v;
                    z_out[(size_t)row * 128 + j * 16 + l15] = f2b(sigm(acc[i][j][v] + bv[j]));
                }
    } else if (mode == 1) {
        float bv[8];
#pragma unroll
        for (int j = 0; j < 8; ++j) bv[j] = br[j * 16 + l15];
#pragma unroll
        for (int i = 0; i < 2; ++i)
#pragma unroll
            for (int j = 0; j < 8; ++j)
#pragma unroll
                for (int v = 0; v < 4; ++v) {
                    int row = rb0 + wv * 32 + i * 16 + q * 4 + v;
                    float r = sigm(acc[i][j][v] + bv[j]);
                    float hh = h_prev[(size_t)row * 128 + j * 16 + l15];
                    rh_out[(size_t)row * 128 + j * 16 + l15] = f2b(r * hh);
                }
    } else {
        float bv[8], gv[8], bev[8];
#pragma unroll
        for (int j = 0; j < 8; ++j) {
            bv[j] = bc[j * 16 + l15];
            gv[j] = gamma[j * 16 + l15];
            bev[j] = beta[j * 16 + l15];
        }
#pragma unroll
        for (int i = 0; i < 2; ++i)
#pragma unroll
            for (int v = 0; v < 4; ++v) {
                const int row = rb0 + wv * 32 + i * 16 + q * 4 + v;
                float hn[8];
                float s = 0.f;
#pragma unroll
                for (int j = 0; j < 8; ++j) {
                    float hc = tanh_fast(acc[i][j][v] + bv[j]);
                    float zz = b2f((uint_t)z_in[(size_t)row * 128 + j * 16 + l15]);
                    float hh = h_prev[(size_t)row * 128 + j * 16 + l15];
                    hn[j] = (1.0f - zz) * hh + zz * hc;
                    s += hn[j];
                }
#pragma unroll
                for (int o = 8; o > 0; o >>= 1) s += __shfl_xor(s, o);  // 16-lane quad
                float mu = s * (1.0f / 128.0f);
                float vv = 0.f;
#pragma unroll
                for (int j = 0; j < 8; ++j) {
                    float d = hn[j] - mu;
                    vv += d * d;
                }
#pragma unroll
                for (int o = 8; o > 0; o >>= 1) vv += __shfl_xor(vv, o);
                float inv = rsqrtf(vv * (1.0f / 128.0f) + LN_EPS);
#pragma unroll
                for (int j = 0; j < 8; ++j)
                    f_out[(size_t)row * 128 + j * 16 + l15] =
                        (hn[j] - mu) * inv * gv[j] + bev[j];
            }
    }
}

// ---------------- launch ----------------

extern "C" void kernel_launch(void* const* d_in, const int* in_sizes, int n_in,
                              void* d_out, int out_size, void* d_ws, size_t ws_size,
                              hipStream_t stream) {
    const float* x = (const float*)d_in[0];
    const int* ei = (const int*)d_in[1];
    const float* h = (const float*)d_in[2];
    const float* Wz = (const float*)d_in[3];
    const float* bz = (const float*)d_in[4];
    const float* Wr = (const float*)d_in[5];
    const float* br = (const float*)d_in[6];
    const float* Wc = (const float*)d_in[7];
    const float* bcv = (const float*)d_in[8];
    const float* gamma = (const float*)d_in[9];
    const float* beta = (const float*)d_in[10];
    float* out = (float*)d_out;

    char* w = (char*)d_ws;
    int* offs = (int*)(w + 0);                    //    40,004 B
    float* dis = (float*)(w + 40960);             //    40,000 B
    int* csr_src = (int*)(w + 81920);             //   640,000 B
    ushort_t* csr_w = (ushort_t*)(w + 721920);    //   320,000 B
    ushort_t* Wt_zr = (ushort_t*)(w + 1041920);   //   131,072 B
    ushort_t* Wt_c = (ushort_t*)(w + 1172992);    //    65,536 B
    ushort_t* agg_x = (ushort_t*)(w + 1239040);   // 20,480,000 B
    ushort_t* agg_h = (ushort_t*)(w + 21719040);  // 20,480,000 B
    ushort_t* z_buf = (ushort_t*)(w + 42199040);  // 20,480,000 B
    ushort_t* rh_bf = (ushort_t*)(w + 62679040);  // 20,480,000 B -> end 83,159,040
    // transients (all dead before gather_xh writes agg_x):
    int* cnt = (int*)(w + 1239040);
    int* cursor = (int*)(w + 1280000);
    int* bsum = (int*)(w + 1320000);
    ushort_t* agg_rh = agg_h;  // agg_h dead after gemm<0>

    hipMemsetAsync(cnt, 0, NN * sizeof(int), stream);
    count_deg<<<EE / 256, 256, 0, stream>>>(ei, cnt);
    scan1<<<40, 256, 0, stream>>>(cnt, offs, bsum);
    scan2<<<1, 64, 0, stream>>>(bsum, offs);
    scan3<<<40, 256, 0, stream>>>(cnt, bsum, offs, cursor, dis);
    fill_csr<<<EE / 256, 256, 0, stream>>>(ei, cursor, dis, csr_src, csr_w);
    wt_k<<<384, 256, 0, stream>>>(Wz, Wr, Wc, Wt_zr, Wt_c);

    gather_xh<<<(BB * NN) / 4, 256, 0, stream>>>(x, h, offs, csr_src, csr_w, dis,
                                                 agg_x, agg_h);
    // z (y=0) and rh (y=1) from one GEMM over [agg_x|agg_h]
    gemm_k<0><<<dim3(80000 / 128, 2), 256, 0, stream>>>(
        agg_x, agg_h, Wt_zr, bz, br, bcv, h, (const ushort_t*)0, gamma, beta,
        z_buf, rh_bf, (float*)0);
    gather_rh<<<(BB * NN) / 4, 256, 0, stream>>>(rh_bf, offs, csr_src, csr_w, dis, agg_rh);
    // out = LN(GRU(tanh([agg_x|agg_rh]@Wc + bc)))
    gemm_k<1><<<dim3(80000 / 128, 1), 256, 0, stream>>>(
        agg_x, agg_rh, Wt_c, bz, br, bcv, h, z_buf, gamma, beta,
        (ushort_t*)0, (ushort_t*)0, out);
}